// Round 1
// baseline (250.875 us; speedup 1.0000x reference)
//
#include <hip/hip_runtime.h>
#include <math.h>

#define D 256          // d_model
#define M 16           // num memory items
#define TAU 0.1f
#define EPSN 1e-12f
#define MEM_STRIDE 260 // floats; 260*4B = 1040B, 16B-aligned rows, de-conflicted banks
#define WAVES_PER_BLOCK 4
#define ROWS_PER_BLOCK 64
#define ITERS (ROWS_PER_BLOCK / WAVES_PER_BLOCK) // 16

__global__ __launch_bounds__(256, 4)
void epm_kernel(const float* __restrict__ q, const float* __restrict__ mem,
                float* __restrict__ ret_out, float* __restrict__ smax_out)
{
    __shared__ __align__(16) float mem_lds[M * MEM_STRIDE]; // raw memory, padded rows
    __shared__ float inv_nm_lds[M];
    // per-wave q buffer: 4 chunks of 64 floats, chunk stride 68 to de-conflict
    __shared__ __align__(16) float qbuf[WAVES_PER_BLOCK * 4 * 68];

    const int tid  = threadIdx.x;
    const int wave = tid >> 6;
    const int lane = tid & 63;
    const int mIdx = lane & 15;   // which memory row this lane dots
    const int cIdx = lane >> 4;   // which 64-element chunk of d

    // ---- stage raw memory into LDS (coalesced float4) ----
    {
        // 16*256 = 4096 floats = 1024 float4; 256 threads -> 4 passes
        const float4* m4 = (const float4*)mem;
        #pragma unroll
        for (int p = 0; p < 4; ++p) {
            int vi  = p * 256 + tid;      // float4 index 0..1023
            int row = vi >> 6;            // 64 float4 per row
            int col = (vi & 63) * 4;
            float4 v = m4[vi];
            *(float4*)&mem_lds[row * MEM_STRIDE + col] = v;
        }
    }
    __syncthreads();

    // ---- per-memory-row inverse norms (threads 0..15, once per block) ----
    if (tid < M) {
        const float4* r4 = (const float4*)&mem_lds[tid * MEM_STRIDE];
        float ss = 0.f;
        #pragma unroll
        for (int j = 0; j < D / 4; ++j) {
            float4 v = r4[j];
            ss += v.x * v.x + v.y * v.y + v.z * v.z + v.w * v.w;
        }
        inv_nm_lds[tid] = 1.0f / fmaxf(sqrtf(ss), EPSN);
    }
    __syncthreads();

    // ---- load this lane's memory slice into registers: mem[mIdx][cIdx*64 + 4j .. +3] ----
    float4 memr[16];
    {
        const float4* src = (const float4*)&mem_lds[mIdx * MEM_STRIDE + cIdx * 64];
        #pragma unroll
        for (int j = 0; j < 16; ++j) memr[j] = src[j];
    }
    const float scale_m = inv_nm_lds[mIdx] * (1.0f / TAU);

    float* myq = &qbuf[wave * (4 * 68)];
    const int row0 = blockIdx.x * ROWS_PER_BLOCK;

    // prefetch first q row (float4-coalesced: lane i holds elements 4i..4i+3)
    int r = row0 + wave;
    float4 qv = ((const float4*)q)[(size_t)r * 64 + lane];

    for (int t = 0; t < ITERS; ++t) {
        // prefetch next row's q early to hide HBM latency
        int tn = (t + 1 < ITERS) ? (t + 1) : t; // clamp (redundant load on last iter)
        int rown = row0 + tn * 4 + wave;
        float4 qnext = ((const float4*)q)[(size_t)rown * 64 + lane];

        // ||q||^2 over all 64 lanes
        float ss = qv.x * qv.x + qv.y * qv.y + qv.z * qv.z + qv.w * qv.w;
        #pragma unroll
        for (int d = 32; d >= 1; d >>= 1) ss += __shfl_xor(ss, d);
        float inv_nq = 1.0f / fmaxf(sqrtf(ss), EPSN);

        // q -> wave-private LDS in chunked layout
        *(float4*)&myq[(lane >> 4) * 68 + (lane & 15) * 4] = qv;
        __syncthreads();

        // dot(q, mem[mIdx]) over chunk cIdx (raw values)
        float acc = 0.f;
        {
            const float4* qs = (const float4*)&myq[cIdx * 68];
            #pragma unroll
            for (int j = 0; j < 16; ++j) {
                float4 a = qs[j];
                float4 b = memr[j];
                acc += a.x * b.x + a.y * b.y + a.z * b.z + a.w * b.w;
            }
        }
        // combine the 4 chunks
        acc += __shfl_xor(acc, 16);
        acc += __shfl_xor(acc, 32);
        float sim = acc * inv_nq * scale_m;   // = cos(q,m)/TAU

        // max over the 16 memory rows (butterfly within aligned 16-groups)
        float smax = sim;
        #pragma unroll
        for (int d = 8; d >= 1; d >>= 1) smax = fmaxf(smax, __shfl_xor(smax, d));

        // rank of this lane's sim among the 16 (strict total order, index tie-break
        // matching top_k's lower-index-first)
        int cnt = 0;
        #pragma unroll
        for (int d = 1; d < 16; ++d) {
            float ov = __shfl_xor(sim, d);
            int om = mIdx ^ d;
            cnt += (ov > sim || (ov == sim && om < mIdx)) ? 1 : 0;
        }

        // broadcast the top-4 (sim, m) to all lanes; exactly 4 lanes (c-duplicates)
        // have each rank k
        float tw[4];
        int   tm[4];
        #pragma unroll
        for (int k = 0; k < 4; ++k) {
            unsigned long long ball = __ballot(cnt == k);
            int src = (int)__builtin_ctzll(ball);
            float sv = __shfl(sim, src);
            tm[k] = src & 15;
            tw[k] = __expf(sv - smax);
        }
        float invd = 1.0f / (tw[0] + tw[1] + tw[2] + tw[3]);

        // retrieved[r][4*lane..4*lane+3] = sum_k w_k * RAW mem[tm_k][...]
        float4 accv = make_float4(0.f, 0.f, 0.f, 0.f);
        #pragma unroll
        for (int k = 0; k < 4; ++k) {
            float4 mv = *(const float4*)&mem_lds[tm[k] * MEM_STRIDE + 4 * lane];
            float w = tw[k];
            accv.x += w * mv.x; accv.y += w * mv.y;
            accv.z += w * mv.z; accv.w += w * mv.w;
        }
        accv.x *= invd; accv.y *= invd; accv.z *= invd; accv.w *= invd;

        ((float4*)ret_out)[(size_t)r * 64 + lane] = accv;
        if (lane == 0) smax_out[r] = smax;

        qv = qnext;
        r = row0 + (t + 1) * 4 + wave;
        __syncthreads(); // qbuf reuse fence before next iteration's write
    }
}

extern "C" void kernel_launch(void* const* d_in, const int* in_sizes, int n_in,
                              void* d_out, int out_size, void* d_ws, size_t ws_size,
                              hipStream_t stream) {
    const float* queries = (const float*)d_in[0];
    const float* memory  = (const float*)d_in[1];
    float* out = (float*)d_out;

    const int rows = in_sizes[0] / D;               // 32*4096 = 131072
    float* ret_out  = out;                          // [rows, 256]
    float* smax_out = out + (size_t)rows * D;       // [rows, 1]

    const int blocks = rows / ROWS_PER_BLOCK;       // 2048
    epm_kernel<<<blocks, 64 * WAVES_PER_BLOCK, 0, stream>>>(queries, memory, ret_out, smax_out);
}

// Round 3
// 242.396 us; speedup vs baseline: 1.0350x; 1.0350x over previous
//
#include <hip/hip_runtime.h>
#include <math.h>

#define D 256          // d_model
#define M 16           // num memory items
#define TAU 0.1f
#define EPSN 1e-12f
#define MEM_STRIDE 260 // floats; 1040 B rows, 16B-aligned
#define NWAVES 4
#define BATCH 16       // rows per wave
#define ROWS_PER_BLOCK (NWAVES * BATCH) // 64

// ---- DPP wave64 sum-reduce (VALU pipe, zero DS traffic) ----
// ctrl/masks must be compile-time constants -> template parameters
template <int CTRL, int ROW_MASK, int BANK_MASK>
__device__ __forceinline__ float dpp_add(float x) {
    int xi = __builtin_bit_cast(int, x);
    int mi = __builtin_amdgcn_update_dpp(0, xi, CTRL, ROW_MASK, BANK_MASK, true);
    return x + __builtin_bit_cast(float, mi);
}
// full-wave sum, returned wave-uniform (readlane 63)
__device__ __forceinline__ float wave_sum(float x) {
    x = dpp_add<0x111, 0xf, 0xf>(x); // row_shr:1
    x = dpp_add<0x112, 0xf, 0xf>(x); // row_shr:2
    x = dpp_add<0x114, 0xf, 0xe>(x); // row_shr:4
    x = dpp_add<0x118, 0xf, 0xc>(x); // row_shr:8
    x = dpp_add<0x142, 0xa, 0xf>(x); // row_bcast:15 (rows 1,3)
    x = dpp_add<0x143, 0xc, 0xf>(x); // row_bcast:31 (rows 2,3)
    int t = __builtin_amdgcn_readlane(__builtin_bit_cast(int, x), 63);
    return __builtin_bit_cast(float, t);
}

__global__ __launch_bounds__(256, 4)
void epm_kernel(const float* __restrict__ q, const float* __restrict__ mem,
                float* __restrict__ ret_out, float* __restrict__ smax_out)
{
    __shared__ __align__(16) float mem_lds[M * MEM_STRIDE];
    __shared__ float inv_nm_lds[M];
    __shared__ __align__(16) float qbuf[NWAVES][4 * 68];   // per-wave q row, chunked+padded
    __shared__ float simbuf[NWAVES][M * 17];               // [m][batch+1 pad] transposed sims
    __shared__ float nbuf[NWAVES][BATCH];                  // ||q||^2 per row
    __shared__ __align__(16) float wbuf[NWAVES][BATCH * 4];// normalized softmax weights
    __shared__ int   mbuf[NWAVES][BATCH];                  // packed top-4 indices

    const int tid  = threadIdx.x;
    const int wv   = tid >> 6;
    const int lane = tid & 63;
    const int m    = lane & 15;   // memory row for dot phase
    const int c    = lane >> 4;   // 64-elem chunk of d

    // ---- stage raw memory into LDS (coalesced float4) ----
    {
        const float4* m4 = (const float4*)mem;
        #pragma unroll
        for (int p = 0; p < 4; ++p) {
            int vi  = p * 256 + tid;
            int row = vi >> 6;
            int col = (vi & 63) * 4;
            float4 v = m4[vi];
            *(float4*)&mem_lds[row * MEM_STRIDE + col] = v;
        }
    }
    __syncthreads();

    if (tid < M) {
        const float4* r4 = (const float4*)&mem_lds[tid * MEM_STRIDE];
        float ss = 0.f;
        #pragma unroll
        for (int j = 0; j < D / 4; ++j) {
            float4 v = r4[j];
            ss += v.x * v.x + v.y * v.y + v.z * v.z + v.w * v.w;
        }
        inv_nm_lds[tid] = 1.0f / fmaxf(sqrtf(ss), EPSN);
    }
    __syncthreads();
    // no more block barriers below: all inter-phase buffers are wave-private

    // this lane's memory slice in registers: mem[m][c*64 .. c*64+63]
    float4 memr[16];
    {
        const float4* src = (const float4*)&mem_lds[m * MEM_STRIDE + c * 64];
        #pragma unroll
        for (int j = 0; j < 16; ++j) memr[j] = src[j];
    }
    const float scale_m = inv_nm_lds[m] * (1.0f / TAU);

    const int wave_row0 = blockIdx.x * ROWS_PER_BLOCK + wv * BATCH;
    float* myq = &qbuf[wv][0];
    float* simw = &simbuf[wv][0];

    // ================= dot phase: 16 rows =================
    float4 qv = ((const float4*)q)[(size_t)wave_row0 * 64 + lane];
    #pragma unroll
    for (int r = 0; r < BATCH; ++r) {
        float4 qn = qv;
        if (r + 1 < BATCH)
            qn = ((const float4*)q)[(size_t)(wave_row0 + r + 1) * 64 + lane];

        // ||q||^2 via DPP (no DS)
        float sq = qv.x * qv.x + qv.y * qv.y + qv.z * qv.z + qv.w * qv.w;
        float ss = wave_sum(sq);
        if (lane == 0) nbuf[wv][r] = ss;

        // stage q row (lane i holds q[4i..4i+3]); chunk layout, stride 68
        *(float4*)&myq[(lane >> 4) * 68 + (lane & 15) * 4] = qv;

        // dot(q, mem[m]) over chunk c
        float acc = 0.f;
        const float4* qs = (const float4*)&myq[c * 68];
        #pragma unroll
        for (int j = 0; j < 16; ++j) {
            float4 a = qs[j];
            float4 b = memr[j];
            acc += a.x * b.x + a.y * b.y + a.z * b.z + a.w * b.w;
        }
        // combine the 4 chunks (the only per-row shuffles)
        acc += __shfl_xor(acc, 16);
        acc += __shfl_xor(acc, 32);
        if (c == 0) simw[m * 17 + r] = acc * scale_m; // raw-dot * inv_nm / tau
        qv = qn;
    }

    // ================= top-k phase: lane = row =================
    if (lane < BATCH) {
        const int r = lane;
        float ssq = nbuf[wv][r];
        float inv_nq = 1.0f / fmaxf(sqrtf(ssq), EPSN);

        // running top-4 with packed (value | index-in-low-nibble) keys
        float k0 = -INFINITY, k1 = -INFINITY, k2 = -INFINITY, k3 = -INFINITY;
        #pragma unroll
        for (int mm = 0; mm < M; ++mm) {
            float s = simw[mm * 17 + r] * inv_nq;           // final sim
            int si = (__builtin_bit_cast(int, s) & ~15) | (15 - mm);
            float ks = __builtin_bit_cast(float, si);
            bool g0 = ks > k0, g1 = ks > k1, g2 = ks > k2, g3 = ks > k3;
            float n3 = g2 ? k2 : (g3 ? ks : k3);
            float n2 = g1 ? k1 : (g2 ? ks : k2);
            float n1 = g0 ? k0 : (g1 ? ks : k1);
            float n0 = g0 ? ks : k0;
            k0 = n0; k1 = n1; k2 = n2; k3 = n3;
        }
        int m0 = 15 - (__builtin_bit_cast(int, k0) & 15);
        int m1 = 15 - (__builtin_bit_cast(int, k1) & 15);
        int m2 = 15 - (__builtin_bit_cast(int, k2) & 15);
        int m3 = 15 - (__builtin_bit_cast(int, k3) & 15);

        float w0 = 1.0f;
        float w1 = __expf(k1 - k0);
        float w2 = __expf(k2 - k0);
        float w3 = __expf(k3 - k0);
        float invd = 1.0f / (w0 + w1 + w2 + w3);

        *(float4*)&wbuf[wv][r * 4] = make_float4(w0 * invd, w1 * invd, w2 * invd, w3 * invd);
        mbuf[wv][r] = m0 | (m1 << 8) | (m2 << 16) | (m3 << 24);

        smax_out[wave_row0 + r] = k0;   // sim_max (64B coalesced per wave)
    }

    // ================= retrieval phase: 16 rows =================
    #pragma unroll
    for (int r = 0; r < BATCH; ++r) {
        float4 w = *(const float4*)&wbuf[wv][r * 4]; // broadcast read
        int mp = mbuf[wv][r];                        // broadcast read
        float4 accv = make_float4(0.f, 0.f, 0.f, 0.f);
        #pragma unroll
        for (int k = 0; k < 4; ++k) {
            int mk = (mp >> (8 * k)) & 15;
            float wk = (k == 0) ? w.x : (k == 1) ? w.y : (k == 2) ? w.z : w.w;
            float4 mv = *(const float4*)&mem_lds[mk * MEM_STRIDE + 4 * lane];
            accv.x += wk * mv.x; accv.y += wk * mv.y;
            accv.z += wk * mv.z; accv.w += wk * mv.w;
        }
        ((float4*)ret_out)[(size_t)(wave_row0 + r) * 64 + lane] = accv;
    }
}

extern "C" void kernel_launch(void* const* d_in, const int* in_sizes, int n_in,
                              void* d_out, int out_size, void* d_ws, size_t ws_size,
                              hipStream_t stream) {
    const float* queries = (const float*)d_in[0];
    const float* memory  = (const float*)d_in[1];
    float* out = (float*)d_out;

    const int rows = in_sizes[0] / D;               // 131072
    float* ret_out  = out;                          // [rows, 256]
    float* smax_out = out + (size_t)rows * D;       // [rows]

    const int blocks = rows / ROWS_PER_BLOCK;       // 2048
    epm_kernel<<<blocks, 64 * NWAVES, 0, stream>>>(queries, memory, ret_out, smax_out);
}